// Round 8
// baseline (182.790 us; speedup 1.0000x reference)
//
#include <hip/hip_runtime.h>
#include <cstdint>

#define HW 200704      // 448*448
#define IMG_W 448
#define NCLS 20
#define NDIM 256
#define NBLK 392       // cam blocks per batch (512 px each)
#define CAPB 12        // per-(class,block) candidate slots; mean 5.12
#define CAPG 2560      // global candidate cap per (b,c); mean 2016
#define TFILT 0.99f
#define LK 260         // padded LDS stride: float4-aligned, 260%32==4

// async global->LDS DMA, 16B per lane, dest = wave-uniform base + lane*16
#define ASYNC_COPY16(gp, lp)                                                   \
  __builtin_amdgcn_global_load_lds(                                            \
      (const __attribute__((address_space(1))) void*)(gp),                     \
      (__attribute__((address_space(3))) void*)(lp), 16, 0, 0)

// ---------------------------------------------------------------------------
// K1: fused [transpose | pseudo-label + weight scatter + candidate filter].
// blocks [0, 2*NBLK): pseudo (async LDS staging); [2*NBLK, 2*NBLK+400): transpose.
__global__ __launch_bounds__(256) void k_front(const float* __restrict__ fmap,
                                               float* __restrict__ fmapT,
                                               const float* __restrict__ cam,
                                               const float* __restrict__ cls_label,
                                               const float* __restrict__ hig_p,
                                               const float* __restrict__ low_p,
                                               const float* __restrict__ bg_p,
                                               float* __restrict__ W,
                                               int* __restrict__ counts,
                                               int* __restrict__ cntBlk,
                                               int* __restrict__ candIdx) {
  __shared__ float sT[NCLS][512];      // 40 KB tile (pseudo) / reused (transpose)
  __shared__ float sLab[NCLS];
  __shared__ int sCnt[NCLS];
  int tid = threadIdx.x;

  if (blockIdx.x >= 2 * NBLK) {
    // ---------------- transpose part: fmap [B,256,784] -> fmapT [B,784,256]
    float (*tile)[33] = (float (*)[33]) & sT[0][0];   // 4224 B of the 40 KB
    int blk = blockIdx.x - 2 * NBLK;
    int b = blk / 200;
    int t = blk % 200;
    int dT = t / 25, sT2 = t % 25;
    int ty = tid >> 5, tx = tid & 31;
#pragma unroll
    for (int r = 0; r < 4; ++r) {
      int d = dT * 32 + ty + r * 8;
      int s = sT2 * 32 + tx;
      if (s < 784) tile[ty + r * 8][tx] = fmap[((size_t)(b * 256 + d)) * 784 + s];
    }
    __syncthreads();
#pragma unroll
    for (int r = 0; r < 4; ++r) {
      int s = sT2 * 32 + ty + r * 8;
      int d = dT * 32 + tx;
      if (s < 784) fmapT[((size_t)(b * 784 + s)) * 256 + d] = tile[tx][ty + r * 8];
    }
    return;
  }

  // ---------------- pseudo part
  int b = blockIdx.x / NBLK;
  int blkInB = blockIdx.x % NBLK;
  int pix0 = blkInB * 512;
  if (tid < NCLS) { sLab[tid] = cls_label[b * NCLS + tid]; sCnt[tid] = 0; }
  int wave = tid >> 6, lane = tid & 63;
  const float* camb = cam + (size_t)b * NCLS * HW + pix0;

  // ---- stage: 10 async 16B DMA per lane, zero VGPR round-trip ----
#pragma unroll
  for (int k = 0; k < 10; ++k) {
    int c = wave * 5 + (k >> 1);
    int off = (k & 1) * 256;                       // wave-uniform float offset
    const float* g = camb + (size_t)c * HW + off + lane * 4;
    ASYNC_COPY16(g, &sT[c][off]);
  }
  __syncthreads();                                  // drains vmcnt before ds_read

  // ---- consume: branchless top-2 + candidate mask (2 px/thread) ----
  float top1[2] = {-1.0f, -1.0f}, sec[2] = {-1.0f, -1.0f};
  int idx1[2] = {0, 0};
  unsigned cm[2] = {0u, 0u};
#pragma unroll
  for (int c = 0; c < NCLS; ++c) {
    float lab = sLab[c];
    float2 t2 = *(const float2*)&sT[c][tid * 2];
    float vv[2] = {t2.x * lab, t2.y * lab};
#pragma unroll
    for (int u = 0; u < 2; ++u) {
      float x = vv[u];
      // ascending c + strict '>' == lowest-index tie-break (JAX top_k)
      bool gt = x > top1[u];
      sec[u] = gt ? top1[u] : fmaxf(sec[u], fminf(x, top1[u]));
      idx1[u] = gt ? c : idx1[u];
      top1[u] = gt ? x : top1[u];
      cm[u] |= (x >= TFILT) ? (1u << c) : 0u;
    }
  }

  // ---- rare side effects (LDS-atomic slot reserve; no global return-atomics) ----
  float hig = hig_p[0], low = low_p[0], bg = bg_p[0];
#pragma unroll
  for (int u = 0; u < 2; ++u) {
    unsigned m = cm[u];
    while (m) {
      int c = __builtin_ctz(m); m &= m - 1u;
      int pos = atomicAdd(&sCnt[c], 1);
      if (pos < CAPB)
        candIdx[(size_t)((b * NCLS + c) * NBLK + blkInB) * CAPB + pos] = pix0 + tid * 2 + u;
    }
    int ps = idx1[u] + 1;
    float t1 = top1[u];
    if (t1 < hig) ps = 255;
    if (t1 < low) ps = 0;
    if (t1 < bg)  ps = 0;
    if ((t1 - sec[u] < 0.3f) && (t1 > hig)) ps = 255;
    if (ps >= 1 && ps <= NCLS) {
      int cls = ps - 1;
      int pix = pix0 + tid * 2 + u;
      int y = pix / IMG_W, x = pix % IMG_W;
      float sy = (y + 0.5f) * 0.0625f - 0.5f; sy = fminf(fmaxf(sy, 0.0f), 27.0f);
      float sx = (x + 0.5f) * 0.0625f - 0.5f; sx = fminf(fmaxf(sx, 0.0f), 27.0f);
      int fy0 = (int)sy, fx0 = (int)sx;
      int fy1 = min(fy0 + 1, 27), fx1 = min(fx0 + 1, 27);
      float wy = sy - (float)fy0, wx = sx - (float)fx0;
      float* Wb = W + (size_t)(b * NCLS + cls) * 784;
      atomicAdd(&Wb[fy0 * 28 + fx0], (1.0f - wy) * (1.0f - wx));
      atomicAdd(&Wb[fy0 * 28 + fx1], (1.0f - wy) * wx);
      atomicAdd(&Wb[fy1 * 28 + fx0], wy * (1.0f - wx));
      atomicAdd(&Wb[fy1 * 28 + fx1], wy * wx);
      atomicAdd(&counts[b * NCLS + cls], 1);
    }
  }
  __syncthreads();
  if (tid < NCLS)
    cntBlk[(b * NCLS + tid) * NBLK + blkInB] = sCnt[tid];
}

// ---------------------------------------------------------------------------
// K2: fused features + loss. 40 blocks x 1024 threads; last-block ticket runs
// the ILP-parallel loss (r7 math, bit-identical).
__global__ __launch_bounds__(1024) void k_feat_loss(const float* __restrict__ fmapT,
                                                    const float* __restrict__ cam,
                                                    const float* __restrict__ Wg,
                                                    const int* __restrict__ counts,
                                                    const int* __restrict__ cntBlk,
                                                    const int* __restrict__ candIdx,
                                                    const float* __restrict__ cls_label,
                                                    const float* __restrict__ proj_w,
                                                    const float* __restrict__ fc_init,
                                                    int* __restrict__ done,
                                                    float* __restrict__ fsm_g,
                                                    float* __restrict__ out) {
  __shared__ float sW[784];
  __shared__ float sPart[4][256];
  __shared__ float cv[CAPG]; __shared__ int ci[CAPG];
  __shared__ float wv[16]; __shared__ int wi[16];
  __shared__ float selV; __shared__ int selI;
  __shared__ int sTop[25];
  __shared__ int sN, sFb, sLast;
  // loss state
  __shared__ float sFsm[NCLS * LK], sFc[NCLS * LK], sPw[NCLS * LK];
  __shared__ float sMat[NCLS * NCLS], sRow[NCLS], sNormI[NCLS], sNormC[NCLS];
  __shared__ int   sZI[NCLS], sZC[NCLS], sQual[NCLS];
  __shared__ float sPres[2][NCLS];
  __shared__ float sScal[2];

  int bc = blockIdx.x;
  int b = bc / NCLS;
  int tid = threadIdx.x;
  int dim = tid & 255, part = tid >> 8;
  bool present = (cls_label[bc] != 0.0f);
  int cnt = counts[bc];
  const float* fT = fmapT + (size_t)b * 784 * 256;
  float res = 0.0f;

  if (present) {
    if (cnt > 0) {
      for (int s = tid; s < 784; s += 1024) sW[s] = Wg[(size_t)bc * 784 + s];
      __syncthreads();
      float a0 = 0.0f, a1 = 0.0f, a2 = 0.0f, a3 = 0.0f;
      int s0 = part * 196;
      for (int s = s0; s < s0 + 196; s += 4) {
        a0 += sW[s]     * fT[(size_t)(s)     * 256 + dim];
        a1 += sW[s + 1] * fT[(size_t)(s + 1) * 256 + dim];
        a2 += sW[s + 2] * fT[(size_t)(s + 2) * 256 + dim];
        a3 += sW[s + 3] * fT[(size_t)(s + 3) * 256 + dim];
      }
      sPart[part][dim] = (a0 + a1) + (a2 + a3);
      __syncthreads();
      if (tid < 256)
        res = ((sPart[0][tid] + sPart[1][tid]) + (sPart[2][tid] + sPart[3][tid]))
              / fmaxf((float)cnt, 1.0f);
    } else {
      if (tid == 0) { sN = 0; sFb = 0; }
      __syncthreads();
      const float* camc = cam + (size_t)bc * HW;   // lab==1 -> valid_cam == cam
      if (tid < NBLK) {
        int cb = cntBlk[(size_t)bc * NBLK + tid];
        if (cb > CAPB) sFb = 1;
        else if (cb > 0) {
          int base = atomicAdd(&sN, cb);
          for (int j = 0; j < cb; ++j) {
            int p = base + j;
            if (p < CAPG) ci[p] = candIdx[(size_t)((size_t)bc * NBLK + tid) * CAPB + j];
          }
        }
      }
      __syncthreads();
      int n = sN;
      bool fb = sFb || (n < 25) || (n > CAPG);
      if (!fb) for (int p = tid; p < n; p += 1024) cv[p] = camc[ci[p]];
      __syncthreads();
      float lastV = 3.0e38f; int lastI = -1;
      for (int r = 0; r < 25; ++r) {
        float bv = -1.0e30f; int bi = 0x7fffffff;
        if (!fb) {
          for (int p = tid; p < n; p += 1024) {
            float vv2 = cv[p]; int ii = ci[p];
            if (((vv2 < lastV) || (vv2 == lastV && ii > lastI)) &&
                ((vv2 > bv) || (vv2 == bv && ii < bi))) { bv = vv2; bi = ii; }
          }
        } else {
          for (int p = tid; p < HW; p += 1024) {
            float vv2 = camc[p];
            if (((vv2 < lastV) || (vv2 == lastV && p > lastI)) &&
                ((vv2 > bv) || (vv2 == bv && p < bi))) { bv = vv2; bi = p; }
          }
        }
        for (int off = 32; off > 0; off >>= 1) {
          float ov = __shfl_xor(bv, off, 64);
          int   oi = __shfl_xor(bi, off, 64);
          if (ov > bv || (ov == bv && oi < bi)) { bv = ov; bi = oi; }
        }
        if ((tid & 63) == 0) { wv[tid >> 6] = bv; wi[tid >> 6] = bi; }
        __syncthreads();
        if (tid == 0) {
          for (int w = 1; w < 16; ++w)
            if (wv[w] > bv || (wv[w] == bv && wi[w] < bi)) { bv = wv[w]; bi = wi[w]; }
          selV = bv; selI = bi; sTop[r] = bi;
        }
        __syncthreads();
        lastV = selV; lastI = selI;
      }
      float at = 0.0f;
      for (int r = part; r < 25; r += 4) {
        int p = sTop[r];
        int y = p / IMG_W, x = p % IMG_W;
        float sy = (y + 0.5f) * 0.0625f - 0.5f; sy = fminf(fmaxf(sy, 0.0f), 27.0f);
        float sx = (x + 0.5f) * 0.0625f - 0.5f; sx = fminf(fmaxf(sx, 0.0f), 27.0f);
        int fy0 = (int)sy, fx0 = (int)sx;
        int fy1 = min(fy0 + 1, 27), fx1 = min(fx0 + 1, 27);
        float wy = sy - (float)fy0, wx = sx - (float)fx0;
        at += (1.0f - wy) * (1.0f - wx) * fT[(size_t)(fy0 * 28 + fx0) * 256 + dim]
            + (1.0f - wy) * wx          * fT[(size_t)(fy0 * 28 + fx1) * 256 + dim]
            + wy          * (1.0f - wx) * fT[(size_t)(fy1 * 28 + fx0) * 256 + dim]
            + wy          * wx          * fT[(size_t)(fy1 * 28 + fx1) * 256 + dim];
      }
      sPart[part][dim] = at;
      __syncthreads();
      if (tid < 256)
        res = ((sPart[0][tid] + sPart[1][tid]) + (sPart[2][tid] + sPart[3][tid])) * (1.0f / 25.0f);
    }
  }
  if (tid < 256) fsm_g[(size_t)bc * 256 + tid] = res;
  __syncthreads();
  // ---- last-block ticket ----
  if (tid == 0) {
    __threadfence();
    int t = atomicAdd(done, 1);
    sLast = (t == 39) ? 1 : 0;
  }
  __syncthreads();
  if (!sLast) return;
  __threadfence();

  // ================= loss (r7 parallel structure, identical math) ==========
  for (int idx = tid; idx < NCLS * NDIM; idx += 1024) {
    int r = idx >> 8, d = idx & 255;
    sFc[r * LK + d] = fc_init[idx];
    sPw[r * LK + d] = proj_w[idx];
  }
  if (tid < 40) sPres[tid / NCLS][tid % NCLS] = cls_label[tid];
  if (tid == 0) { sScal[0] = 0.0f; sScal[1] = 0.0f; }
  __syncthreads();

  for (int bb = 0; bb < 2; ++bb) {
    for (int idx = tid; idx < NCLS * NDIM; idx += 1024)
      sFsm[(idx >> 8) * LK + (idx & 255)] = fsm_g[bb * NCLS * NDIM + idx];
    __syncthreads();
    {
      int g = tid >> 3, sub = tid & 7;
      if (g < 40) {
        const float* row = (g < NCLS) ? &sFsm[g * LK] : &sFc[(g - NCLS) * LK];
        float a0 = 0.0f, a1 = 0.0f, a2 = 0.0f, a3 = 0.0f;
        int d0 = sub * 32;
#pragma unroll
        for (int d = d0; d < d0 + 32; d += 8) {
          float4 x = *(const float4*)&row[d];
          float4 y = *(const float4*)&row[d + 4];
          a0 += x.x * x.x + x.y * x.y;
          a1 += x.z * x.z + x.w * x.w;
          a2 += y.x * y.x + y.y * y.y;
          a3 += y.z * y.z + y.w * y.w;
        }
        float s = (a0 + a1) + (a2 + a3);
        s += __shfl_xor(s, 1, 64);
        s += __shfl_xor(s, 2, 64);
        s += __shfl_xor(s, 4, 64);
        if (sub == 0) {
          if (g < NCLS) { sNormI[g] = fmaxf(sqrtf(s), 1e-12f); sZI[g] = (s == 0.0f); }
          else { sNormC[g - NCLS] = fmaxf(sqrtf(s), 1e-12f); sZC[g - NCLS] = (s == 0.0f); }
        }
      }
    }
    __syncthreads();
    {
      int pair = tid >> 1, sub = tid & 1;
      if (pair < 400) {
        int i = pair / NCLS, j = pair % NCLS;
        float c0;
        if (sZI[i] || sZC[j]) c0 = 0.0f;
        else {
          const float* ra = &sFsm[i * LK];
          const float* rb = &sFc[j * LK];
          float a0 = 0.0f, a1 = 0.0f, a2 = 0.0f, a3 = 0.0f;
          int d0 = sub * 128;
          for (int d = d0; d < d0 + 128; d += 8) {
            float4 x  = *(const float4*)&ra[d];
            float4 y  = *(const float4*)&rb[d];
            float4 x2 = *(const float4*)&ra[d + 4];
            float4 y2 = *(const float4*)&rb[d + 4];
            a0 += x.x * y.x + x.y * y.y;
            a1 += x.z * y.z + x.w * y.w;
            a2 += x2.x * y2.x + x2.y * y2.y;
            a3 += x2.z * y2.z + x2.w * y2.w;
          }
          float acc = (a0 + a1) + (a2 + a3);
          acc += __shfl_xor(acc, 1, 64);
          c0 = fabsf(acc / (sNormI[i] * sNormC[j]));
        }
        if (sub == 0) sMat[pair] = fminf(fmaxf(c0, 1e-5f), 1.0f - 1e-5f);
      }
    }
    __syncthreads();
    {
      int i = tid >> 5, jj = tid & 31;
      if (i < NCLS) {
        float pres = (sPres[bb][i] > 0.5f) ? 1.0f : 0.0f;
        float contrib = 0.0f, omv = -3.0e38f;
        if (jj < NCLS) {
          float c0 = sMat[i * NCLS + jj];
          float ident = (jj == i) ? pres : 0.0f;
          contrib = ident * logf(c0) + (1.0f - ident) * log1pf(-c0);
          if (jj != i) omv = c0;
        }
#pragma unroll
        for (int off = 1; off < 32; off <<= 1) {
          contrib += __shfl_xor(contrib, off, 64);
          omv = fmaxf(omv, __shfl_xor(omv, off, 64));
        }
        if (jj == 0) { sRow[i] = contrib; sQual[i] = (pres > 0.5f && omv < 0.6f) ? 1 : 0; }
      }
    }
    __syncthreads();
    if (tid == 0) {
      float s = 0.0f;
      for (int r = 0; r < NCLS; ++r) s += sRow[r];
      sScal[0] -= s / 400.0f;
    }
    __syncthreads();
    {
      int pair = tid >> 1, sub = tid & 1;
      if (pair < 400) {
        int i = pair / NCLS, j = pair % NCLS;
        float acc = 0.0f;
        if (!sZI[i]) {
          const float* ra = &sFsm[i * LK];
          const float* rb = &sPw[j * LK];
          float a0 = 0.0f, a1 = 0.0f, a2 = 0.0f, a3 = 0.0f;
          int d0 = sub * 128;
          for (int d = d0; d < d0 + 128; d += 8) {
            float4 x  = *(const float4*)&ra[d];
            float4 y  = *(const float4*)&rb[d];
            float4 x2 = *(const float4*)&ra[d + 4];
            float4 y2 = *(const float4*)&rb[d + 4];
            a0 += x.x * y.x + x.y * y.y;
            a1 += x.z * y.z + x.w * y.w;
            a2 += x2.x * y2.x + x2.y * y2.y;
            a3 += x2.z * y2.z + x2.w * y2.w;
          }
          acc = (a0 + a1) + (a2 + a3);
          acc += __shfl_xor(acc, 1, 64);
        }
        if (sub == 0) sMat[pair] = acc;
      }
    }
    __syncthreads();
    {
      int i = tid >> 5, jj = tid & 31;
      if (i < NCLS) {
        float l = (jj < NCLS) ? sMat[i * NCLS + jj] : -3.0e38f;
        float m = l;
#pragma unroll
        for (int off = 1; off < 32; off <<= 1) m = fmaxf(m, __shfl_xor(m, off, 64));
        float e = (jj < NCLS) ? expf(l - m) : 0.0f;
        float S = e;
#pragma unroll
        for (int off = 1; off < 32; off <<= 1) S += __shfl_xor(S, off, 64);
        float term = 0.0f;
        if (jj < NCLS) {
          float p = e / S;
          term = (jj == i) ? fmaxf(logf(p), -100.0f) : fmaxf(log1pf(-p), -100.0f);
        }
#pragma unroll
        for (int off = 1; off < 32; off <<= 1) term += __shfl_xor(term, off, 64);
        if (jj == 0) sRow[i] = -term / 20.0f;
      }
    }
    __syncthreads();
    if (tid == 0) {
      float add = 0.0f; int nq = 0;
      for (int r = 0; r < NCLS; ++r) if (sQual[r]) { add += sRow[r]; nq++; }
      float lc = sScal[1] + add;
      if (nq > 0) lc = lc / fmaxf((float)nq, 1.0f);
      sScal[1] = lc;
    }
    for (int idx = tid; idx < NCLS * NDIM; idx += 1024) {
      int r = idx >> 8, d = idx & 255;
      if (sQual[r]) sFc[r * LK + d] = 0.95f * sFc[r * LK + d] + 0.05f * sFsm[r * LK + d];
    }
    __syncthreads();
  }
  if (tid == 0) out[0] = sScal[0] + sScal[1];
}

// ---------------------------------------------------------------------------
extern "C" void kernel_launch(void* const* d_in, const int* in_sizes, int n_in,
                              void* d_out, int out_size, void* d_ws, size_t ws_size,
                              hipStream_t stream) {
  const float* fmap      = (const float*)d_in[0];
  const float* cam       = (const float*)d_in[1];
  const float* cls_label = (const float*)d_in[2];
  const float* proj_w    = (const float*)d_in[3];
  const float* fc_init   = (const float*)d_in[4];
  const float* hig       = (const float*)d_in[5];
  const float* low       = (const float*)d_in[6];
  const float* bg        = (const float*)d_in[7];
  float* out = (float*)d_out;

  char* ws = (char*)d_ws;
  float* W       = (float*)(ws);                 // 125440 B
  int*   counts  = (int*)  (ws + 125440);        // 160 B
  int*   done    = (int*)  (ws + 125600);        // 32 B
  int*   cntBlk  = (int*)  (ws + 125632);        // 62720 B
  int*   candIdx = (int*)  (ws + 188352);        // 752640 B
  float* fsm     = (float*)(ws + 940992);        // 40960 B
  float* fmapT   = (float*)(ws + 981952);        // 1605632 B

  hipMemsetAsync(ws, 0, 125632, stream);         // zero W + counts + done
  k_front    <<<2 * NBLK + 400,  256, 0, stream>>>(fmap, fmapT, cam, cls_label,
                                                   hig, low, bg, W, counts, cntBlk, candIdx);
  k_feat_loss<<<            40, 1024, 0, stream>>>(fmapT, cam, W, counts, cntBlk, candIdx,
                                                   cls_label, proj_w, fc_init, done, fsm, out);
}